// Round 4
// baseline (221.880 us; speedup 1.0000x reference)
//
#include <hip/hip_runtime.h>
#include <stdint.h>

#define BB 8
#define TT 256
#define DD 256
#define NSTEP 12
#define NNEG 100
#define SLOTP 104   // padded slots (1 positive + 100 negatives + 3 pad), uint16 rows

typedef _Float16 f16x8 __attribute__((ext_vector_type(8)));
typedef float f32x4 __attribute__((ext_vector_type(4)));

// ---------------- f32 -> OCP e4m3fn ----------------
__device__ __forceinline__ uint32_t f32_to_e4m3(float x) {
#if __has_builtin(__builtin_amdgcn_cvt_pk_fp8_f32)
  return (uint32_t)__builtin_amdgcn_cvt_pk_fp8_f32(x, x, 0, false) & 0xFFu;
#else
  union { float f; uint32_t u; } c; c.f = x;
  uint32_t s = (c.u >> 24) & 0x80u;
  float a = fabsf(x);
  if (!(a < 448.f)) return s | 0x7Eu;
  int e; float mf = frexpf(a, &e); (void)mf;
  e -= 1;
  int E = e < -6 ? -6 : e;
  float q = nearbyintf(ldexpf(a, 3 - E));
  int qi = (int)q;
  if (qi == 0) return s;
  while (qi >= 16) { qi >>= 1; ++E; }
  if (qi < 8) return s | (uint32_t)qi;                       // subnormal (E==-6)
  return s | ((uint32_t)(E + 7) << 3) | (uint32_t)(qi & 7);
#endif
}

__device__ __forceinline__ uint32_t f32x4_to_e4m3x4(float x, float y, float z, float w) {
#if __has_builtin(__builtin_amdgcn_cvt_pk_fp8_f32)
  int lo = __builtin_amdgcn_cvt_pk_fp8_f32(x, y, 0, false);
  return (uint32_t)__builtin_amdgcn_cvt_pk_fp8_f32(z, w, lo, true);
#else
  return f32_to_e4m3(x) | (f32_to_e4m3(y) << 8) | (f32_to_e4m3(z) << 16) | (f32_to_e4m3(w) << 24);
#endif
}

__device__ __forceinline__ long pk64(uint2 v) {
  union { uint2 u; long l; } c; c.u = v; return c.l;
}

// ---------------- Threefry2x32 (JAX-compatible), host+device ----------------
__host__ __device__ __forceinline__ void tf2x32(uint32_t k0, uint32_t k1,
                                                uint32_t x0, uint32_t x1,
                                                uint32_t &y0, uint32_t &y1) {
  const uint32_t ks2 = k0 ^ k1 ^ 0x1BD11BDAu;
  x0 += k0; x1 += k1;
#define TF_R(r) { x0 += x1; x1 = (x1 << (r)) | (x1 >> (32 - (r))); x1 ^= x0; }
  TF_R(13) TF_R(15) TF_R(26) TF_R(6)
  x0 += k1; x1 += ks2 + 1u;
  TF_R(17) TF_R(29) TF_R(16) TF_R(24)
  x0 += ks2; x1 += k0 + 2u;
  TF_R(13) TF_R(15) TF_R(26) TF_R(6)
  x0 += k0; x1 += k1 + 3u;
  TF_R(17) TF_R(29) TF_R(16) TF_R(24)
  x0 += k1; x1 += ks2 + 4u;
  TF_R(13) TF_R(15) TF_R(26) TF_R(6)
  x0 += ks2; x1 += k0 + 5u;
#undef TF_R
  y0 = x0; y1 = x1;
}

// ---------------- host-computed per-step constants ----------------
struct IdxParams {
  uint32_t k1x[NSTEP], k1y[NSTEP], k2x[NSTEP], k2y[NSTEP];
  uint32_t mult[NSTEP];
  uint32_t Msp[NSTEP], Ssp[NSTEP], Asp[NSTEP];   // magic for span = 8*T2
  uint32_t Mt2[NSTEP], St2[NSTEP], At2[NSTEP];   // magic for T2
};

// Hacker's Delight 10-9 unsigned magic
static void magicu(uint32_t d, uint32_t* M, uint32_t* s, uint32_t* a) {
  uint32_t p, nc, delta, q1, r1, q2, r2;
  *a = 0;
  nc = 0xFFFFFFFFu - (0u - d) % d;
  p = 31;
  q1 = 0x80000000u / nc; r1 = 0x80000000u - q1 * nc;
  q2 = 0x7FFFFFFFu / d;  r2 = 0x7FFFFFFFu - q2 * d;
  do {
    p = p + 1;
    if (r1 >= nc - r1) { q1 = 2*q1 + 1; r1 = 2*r1 - nc; }
    else               { q1 = 2*q1;     r1 = 2*r1; }
    if (r2 + 1 >= d - r2) {
      if (q2 >= 0x7FFFFFFFu) *a = 1;
      q2 = 2*q2 + 1; r2 = 2*r2 + 1 - d;
    } else {
      if (q2 >= 0x80000000u) *a = 1;
      q2 = 2*q2; r2 = 2*r2 + 1;
    }
    delta = d - 1 - r2;
  } while (p < 64 && (q1 < delta || (q1 == delta && r1 == 0)));
  *M = q2 + 1; *s = p - 32;
}

__device__ __forceinline__ uint32_t mdiv(uint32_t n, uint32_t M, uint32_t s, uint32_t a) {
  uint32_t q = __umulhi(n, M);
  if (a) { q = ((n - q) >> 1) + q; return q >> (s - 1); }
  return q >> s;
}

// ------------- prep: tgt-l2norm->e4m3, ctx->f16, W->f16, Sbuf zero, idx table -------------
// blocks [0,512): targets; [512,1024): ctx; [1024,1792): W; [1792,1888): zero Sbuf;
// [1888,1888+9984): index table.
__global__ __launch_bounds__(256) void prep_kernel(const IdxParams P,
                                                   const float* __restrict__ tgt,
                                                   const float* __restrict__ ctx,
                                                   const float* __restrict__ W,
                                                   uint8_t* __restrict__ tn8,
                                                   _Float16* __restrict__ ctxh,
                                                   _Float16* __restrict__ Wh,
                                                   uint16_t* __restrict__ idxTab,
                                                   float* __restrict__ Sbuf,
                                                   float* __restrict__ out) {
  const int bx = blockIdx.x;
  const int tid = threadIdx.x;
  if (bx == 0 && tid == 0) out[0] = 0.f;
  if (bx < 512) {                                        // tgt: normalize -> e4m3
    const int lane = tid & 63;
    const int row = bx * 4 + (tid >> 6);
    float4 v = ((const float4*)(tgt + (size_t)row * DD))[lane];
    float ss = v.x*v.x + v.y*v.y + v.z*v.z + v.w*v.w;
#pragma unroll
    for (int off = 1; off < 64; off <<= 1) ss += __shfl_xor(ss, off, 64);
    const float sc = 1.0f / fmaxf(sqrtf(ss), 1e-12f);
    ((uint32_t*)(tn8 + (size_t)row * DD))[lane] =
        f32x4_to_e4m3x4(v.x * sc, v.y * sc, v.z * sc, v.w * sc);
  } else if (bx < 1792) {
    const int lane = tid & 63;
    union { _Float16 h[4]; uint2 u; } o;
    if (bx < 1024) {                                     // ctx: plain convert
      const int row = (bx - 512) * 4 + (tid >> 6);
      float4 v = ((const float4*)(ctx + (size_t)row * DD))[lane];
      o.h[0] = (_Float16)v.x; o.h[1] = (_Float16)v.y;
      o.h[2] = (_Float16)v.z; o.h[3] = (_Float16)v.w;
      ((uint2*)(ctxh + (size_t)row * DD))[lane] = o.u;
    } else {                                             // W: plain convert (3072 rows)
      const int row = (bx - 1024) * 4 + (tid >> 6);
      float4 v = ((const float4*)(W + (size_t)row * DD))[lane];
      o.h[0] = (_Float16)v.x; o.h[1] = (_Float16)v.y;
      o.h[2] = (_Float16)v.z; o.h[3] = (_Float16)v.w;
      ((uint2*)(Wh + (size_t)row * DD))[lane] = o.u;
    }
  } else if (bx < 1888) {                                // zero Sbuf (12*2048 f32)
    Sbuf[(bx - 1792) * 256 + tid] = 0.f;
  } else {                                               // index table: 832 blocks per step
    const int ib = bx - 1888;                            // 0..9983
    const int si = ib / 832;                             // block-uniform -> scalar P loads
    const int step = si + 1;
    const uint32_t T2 = (uint32_t)(TT - step);
    const uint32_t nloc = (uint32_t)(ib - si * 832) * 256u + (uint32_t)tid;  // 0..212991
    const uint32_t m = nloc / 104u;                      // b*256 + t
    const uint32_t slot = nloc - m * 104u;
    const uint32_t t = m & 255u;
    const uint32_t b = m >> 8;
    uint32_t v = 0u;
    if (t < T2 && slot <= (uint32_t)NNEG) {
      if (slot == 0u) {
        v = b * TT + t + (uint32_t)step;                 // positive row
      } else {
        const uint32_t j = (b * T2 + t) * NNEG + (slot - 1u);
        uint32_t h0, h1, l0, l1;
        tf2x32(P.k1x[si], P.k1y[si], 0u, j, h0, h1);
        tf2x32(P.k2x[si], P.k2y[si], 0u, j, l0, l1);
        const uint32_t span = 8u * T2;
        const uint32_t Msp = P.Msp[si], Ssp = P.Ssp[si], Asp = P.Asp[si];
        const uint32_t hm = h0 - mdiv(h0, Msp, Ssp, Asp) * span;
        const uint32_t lm = l0 - mdiv(l0, Msp, Ssp, Asp) * span;
        const uint32_t off = hm * P.mult[si] + lm;
        const uint32_t om = off - mdiv(off, Msp, Ssp, Asp) * span;
        const uint32_t bbq = mdiv(om, P.Mt2[si], P.St2[si], P.At2[si]);
        const uint32_t tt = om - bbq * T2;
        v = bbq * TT + tt + (uint32_t)step;
      }
    }
    idxTab[(size_t)si * (2048u * 104u) + nloc] = (uint16_t)v;
  }
}

// ------------- query GEMM (MFMA f16) + bias + l2norm -> e4m3 -------------
// grid (64 m-tiles of 32 rows, 12 steps), block 256 = 4 waves.
__global__ __launch_bounds__(256) void qgemm_mfma_kernel(const _Float16* __restrict__ ctxh,
                                                         const _Float16* __restrict__ Wh,
                                                         const float* __restrict__ bias,
                                                         uint8_t* __restrict__ qn8) {
  const int mt  = blockIdx.x;           // 0..63
  const int s   = blockIdx.y;           // 0..11
  const int tid = threadIdx.x;
  const int w   = tid >> 6;
  const int lane = tid & 63;
  const int sl = lane & 15;
  const int q  = lane >> 4;
  const int m0 = mt * 32;

  const _Float16* Arow0 = ctxh + ((size_t)(m0 + sl)) * DD + q * 8;
  const _Float16* Arow1 = Arow0 + (size_t)16 * DD;
  const _Float16* Bbase = Wh + (size_t)s * DD * DD + ((size_t)(w * 64 + sl)) * DD + q * 8;

  f32x4 acc[2][4];
#pragma unroll
  for (int mi = 0; mi < 2; ++mi)
#pragma unroll
    for (int nt = 0; nt < 4; ++nt) acc[mi][nt] = f32x4{0, 0, 0, 0};

#pragma unroll
  for (int k0 = 0; k0 < 8; ++k0) {
    const f16x8 a0 = *(const f16x8*)(Arow0 + k0 * 32);
    const f16x8 a1 = *(const f16x8*)(Arow1 + k0 * 32);
#pragma unroll
    for (int nt = 0; nt < 4; ++nt) {
      const f16x8 b = *(const f16x8*)(Bbase + (size_t)nt * 16 * DD + k0 * 32);
      acc[0][nt] = __builtin_amdgcn_mfma_f32_16x16x32_f16(a0, b, acc[0][nt], 0, 0, 0);
      acc[1][nt] = __builtin_amdgcn_mfma_f32_16x16x32_f16(a1, b, acc[1][nt], 0, 0, 0);
    }
  }
  const float* bp = bias + (size_t)s * DD + w * 64 + sl;
  __shared__ float part[4][32];
#pragma unroll
  for (int mi = 0; mi < 2; ++mi) {
#pragma unroll
    for (int nt = 0; nt < 4; ++nt) {
      const float bv = bp[nt * 16];
#pragma unroll
      for (int r = 0; r < 4; ++r) acc[mi][nt][r] += bv;
    }
    float ss[4];
#pragma unroll
    for (int r = 0; r < 4; ++r) {
      float v = 0.f;
#pragma unroll
      for (int nt = 0; nt < 4; ++nt) v += acc[mi][nt][r] * acc[mi][nt][r];
      ss[r] = v;
    }
#pragma unroll
    for (int off = 1; off < 16; off <<= 1) {
#pragma unroll
      for (int r = 0; r < 4; ++r) ss[r] += __shfl_xor(ss[r], off, 64);
    }
    if (sl == 0) {
#pragma unroll
      for (int r = 0; r < 4; ++r) part[w][mi * 16 + q * 4 + r] = ss[r];
    }
  }
  __syncthreads();
#pragma unroll
  for (int mi = 0; mi < 2; ++mi) {
#pragma unroll
    for (int r = 0; r < 4; ++r) {
      const int row = q * 4 + r;
      const float tot = part[0][mi * 16 + row] + part[1][mi * 16 + row]
                      + part[2][mi * 16 + row] + part[3][mi * 16 + row];
      const float sc = 1.0f / fmaxf(sqrtf(tot), 1e-12f);
      uint8_t* outp = qn8 + (((size_t)s * (BB * TT)) + m0 + mi * 16 + row) * DD + w * 64 + sl;
#pragma unroll
      for (int nt = 0; nt < 4; ++nt)
        outp[nt * 16] = (uint8_t)f32_to_e4m3(acc[mi][nt][r] * sc);
    }
  }
}

// ------------- scoring v5: panel-dense fp8 MFMA + count-weighted exp accumulate -------------
// grid (4 k-panels of 512, 64 q-tiles of 32, 12 steps), block 256 = 4 waves.
// No score materialization: each lane folds cnt[q][key]*exp(10*score) from its accumulator.
__global__ __launch_bounds__(256, 4) void score_kernel(const uint8_t* __restrict__ qn8,
                                                       const uint8_t* __restrict__ tn8,
                                                       const uint16_t* __restrict__ idxTab,
                                                       float* __restrict__ Sbuf,
                                                       float* __restrict__ X0) {
  const int p   = blockIdx.x;           // panel 0..3 (keys p*512 .. +512)
  const int qt  = blockIdx.y;           // 0..63
  const int si  = blockIdx.z;           // 0..11
  const int step = si + 1;
  const int b   = qt >> 3;
  const int t0  = (qt & 7) * 32;
  const int tid = threadIdx.x;
  const int w   = tid >> 6;
  const int l   = tid & 63;
  const int q16 = l & 15;
  const int kh  = l >> 4;

  __shared__ __align__(16) uint8_t Kl[64 * 256];      // 16KB K chunk (swizzled)
  __shared__ __align__(16) uint8_t cnt[32 * 512];     // 16KB slot-multiplicity (swizzled)
  __shared__ float eLds[32];

  // zero cnt (64B/thread) + eLds
#pragma unroll
  for (int i = 0; i < 4; ++i)
    ((uint4*)cnt)[tid * 4 + i] = uint4{0, 0, 0, 0};
  if (tid < 32) eLds[tid] = 0.f;

  // B-frags direct from L2: 2 query groups x 8 k-steps, 8B each
  uint2 qv[2][8];
#pragma unroll
  for (int qg = 0; qg < 2; ++qg) {
    const uint8_t* qrow = qn8 + ((size_t)si * 2048 + b * 256 + t0 + qg * 16 + q16) * DD + kh * 8;
#pragma unroll
    for (int k0 = 0; k0 < 8; ++k0) qv[qg][k0] = *(const uint2*)(qrow + k0 * 32);
  }
  __syncthreads();

  // build cnt: thread q (<32) scans its 101 slots, keeps panel-local ones.
  // swizzle: byte addr = q*512 + (key ^ ((q&7)<<3)) — row-owned, no races.
  if (tid < 32) {
    const uint16_t* gi = idxTab + ((size_t)si * 2048 + b * 256 + t0 + tid) * SLOTP;
    uint8_t* crow = cnt + tid * 512;
    const int sw = (tid & 7) << 3;
#pragma unroll 4
    for (int s = 0; s <= NNEG; ++s) {
      const int R = (int)gi[s];
      if ((R >> 9) == p) crow[(R & 511) ^ sw] += 1;
    }
  }
  __syncthreads();

  const int posrow = b * 256 + t0 + q16 + step;        // for X0 detection (per qg add 16)
  float esum0 = 0.f, esum1 = 0.f;

  for (int c = 0; c < 8; ++c) {                        // 8 chunks x 64 key rows
    if (c) __syncthreads();                            // protect Kl from prev readers
    const uint8_t* kg = tn8 + ((size_t)p * 512 + c * 64) * DD;
#pragma unroll
    for (int i = tid; i < 1024; i += 256) {
      const int row = i >> 4, col = i & 15;
      uint4 v = *(const uint4*)(kg + row * 256 + col * 16);
      *(uint4*)(Kl + row * 256 + ((col * 16) ^ ((row & 7) << 4))) = v;
    }
    __syncthreads();

    const int krow = w * 16 + q16;                     // wave w owns 16-key tile w
    uint2 av[8];
#pragma unroll
    for (int k0 = 0; k0 < 8; ++k0)
      av[k0] = *(const uint2*)(Kl + krow * 256 + ((kh * 8 + k0 * 32) ^ ((krow & 7) << 4)));

    f32x4 a00 = {0,0,0,0}, a01 = {0,0,0,0}, a10 = {0,0,0,0}, a11 = {0,0,0,0};
#pragma unroll
    for (int k0 = 0; k0 < 8; k0 += 2) {
      a00 = __builtin_amdgcn_mfma_f32_16x16x32_fp8_fp8(pk64(av[k0]),     pk64(qv[0][k0]),     a00, 0, 0, 0);
      a10 = __builtin_amdgcn_mfma_f32_16x16x32_fp8_fp8(pk64(av[k0]),     pk64(qv[1][k0]),     a10, 0, 0, 0);
      a01 = __builtin_amdgcn_mfma_f32_16x16x32_fp8_fp8(pk64(av[k0 + 1]), pk64(qv[0][k0 + 1]), a01, 0, 0, 0);
      a11 = __builtin_amdgcn_mfma_f32_16x16x32_fp8_fp8(pk64(av[k0 + 1]), pk64(qv[1][k0 + 1]), a11, 0, 0, 0);
    }
    // lane holds D[key-in-tile = kh*4+r][q-in-group = q16] for both q groups
    const int kb = c * 64 + w * 16 + kh * 4;           // aligned-4 base key
#pragma unroll
    for (int qg = 0; qg < 2; ++qg) {
      const int q = qg * 16 + q16;
      const uint32_t c4 = *(const uint32_t*)(cnt + q * 512 + (kb ^ ((q & 7) << 3)));
      const f32x4 va = qg ? a10 : a00;
      const f32x4 vb = qg ? a11 : a01;
      float es = 0.f;
#pragma unroll
      for (int r = 0; r < 4; ++r) {
        const float x = 10.0f * (va[r] + vb[r]);
        const float cf = (float)((c4 >> (8 * r)) & 255u);
        es = fmaf(cf, __expf(x), es);
        if (kb + r == posrow + qg * 16)
          X0[(size_t)si * 2048 + b * 256 + t0 + q] = x;
      }
      if (qg) esum1 += es; else esum0 += es;
    }
  }

  // reduce: lanes l, l+16, l+32, l+48 share q = qg*16 + (l&15)
  esum0 += __shfl_xor(esum0, 16, 64); esum0 += __shfl_xor(esum0, 32, 64);
  esum1 += __shfl_xor(esum1, 16, 64); esum1 += __shfl_xor(esum1, 32, 64);
  if (l < 16) {
    atomicAdd(&eLds[l], esum0);
    atomicAdd(&eLds[16 + l], esum1);
  }
  __syncthreads();
  if (tid < 32)
    atomicAdd(&Sbuf[si * 2048 + b * 256 + t0 + tid], eLds[tid]);
}

// ---------------- final: loss = mean over valid q of (log S - x0), scaled ----------------
__global__ __launch_bounds__(256) void final_kernel(const float* __restrict__ Sbuf,
                                                    const float* __restrict__ X0,
                                                    float* __restrict__ out) {
  const int idx = blockIdx.x * 256 + threadIdx.x;   // 96 blocks -> 24576
  float v = 0.f;
  const int si = idx >> 11, m = idx & 2047, t = m & 255;
  const int T2 = TT - (si + 1);
  if (t < T2)
    v = (logf(Sbuf[idx]) - X0[idx]) / (12.0f * (float)(BB * T2));
#pragma unroll
  for (int off = 1; off < 64; off <<= 1) v += __shfl_xor(v, off, 64);
  __shared__ float ws[4];
  if ((threadIdx.x & 63) == 0) ws[threadIdx.x >> 6] = v;
  __syncthreads();
  if (threadIdx.x == 0)
    atomicAdd(out, ws[0] + ws[1] + ws[2] + ws[3]);
}

extern "C" void kernel_launch(void* const* d_in, const int* in_sizes, int n_in,
                              void* d_out, int out_size, void* d_ws, size_t ws_size,
                              hipStream_t stream) {
  const float* ctx  = (const float*)d_in[0];
  const float* tgt  = (const float*)d_in[1];
  const float* W    = (const float*)d_in[2];
  const float* bias = (const float*)d_in[3];
  float* out = (float*)d_out;

  uint8_t* tn8   = (uint8_t*)d_ws;                               // 512 KB
  _Float16* ctxh = (_Float16*)(tn8 + (size_t)BB * TT * DD);      // 1 MB
  _Float16* Wh   = ctxh + (size_t)BB * TT * DD;                  // 1.5 MB
  uint8_t* qn8   = (uint8_t*)(Wh + (size_t)NSTEP * DD * DD);     // 6.29 MB
  uint16_t* idxTab = (uint16_t*)(qn8 + (size_t)NSTEP * BB * TT * DD); // 5.11 MB
  float* Sbuf = (float*)(idxTab + (size_t)NSTEP * 2048 * SLOTP); // 96 KB
  float* X0   = Sbuf + (size_t)NSTEP * 2048;                     // 96 KB

  // host-side per-step constants (deterministic; same every call)
  IdxParams P;
  for (int s = 0; s < NSTEP; ++s) {
    uint32_t a, b;
    tf2x32(0u, 1234u, 0u, (uint32_t)(s + 1), a, b);              // fold_in(key(1234), step)
    uint32_t h1a, h1b, h2a, h2b;
    tf2x32(a, b, 0u, 2u, h1a, h1b);                              // split -> k1
    tf2x32(a, b, 1u, 3u, h2a, h2b);                              // split -> k2
    P.k1x[s] = h1a; P.k1y[s] = h1b; P.k2x[s] = h2a; P.k2y[s] = h2b;
    const uint32_t T2 = (uint32_t)(TT - (s + 1));
    const uint32_t span = 8u * T2;
    uint32_t m = 65536u % span;
    P.mult[s] = (uint32_t)(((uint64_t)m * m) % span);
    magicu(span, &P.Msp[s], &P.Ssp[s], &P.Asp[s]);
    magicu(T2,   &P.Mt2[s], &P.St2[s], &P.At2[s]);
  }

  hipLaunchKernelGGL(prep_kernel, dim3(1888 + 12 * 832), dim3(256), 0, stream,
                     P, tgt, ctx, W, tn8, ctxh, Wh, idxTab, Sbuf, out);
  hipLaunchKernelGGL(qgemm_mfma_kernel, dim3(64, NSTEP), dim3(256), 0, stream,
                     ctxh, Wh, bias, qn8);
  hipLaunchKernelGGL(score_kernel, dim3(4, 64, NSTEP), dim3(256), 0, stream,
                     qn8, tn8, idxTab, Sbuf, X0);
  hipLaunchKernelGGL(final_kernel, dim3(96), dim3(256), 0, stream,
                     Sbuf, X0, out);
}

// Round 5
// 129.888 us; speedup vs baseline: 1.7082x; 1.7082x over previous
//
#include <hip/hip_runtime.h>
#include <stdint.h>

#define BB 8
#define TT 256
#define DD 256
#define NSTEP 12
#define NNEG 100
#define SLOTP 104                 // padded slots (1 positive + 100 negatives + 3 pad)
#define NPART (255 * BB * NSTEP)

typedef _Float16 f16x8 __attribute__((ext_vector_type(8)));
typedef float f32x4 __attribute__((ext_vector_type(4)));

// ---------------- int8 dot4 ----------------
__device__ __forceinline__ int sdot4(int a, int b, int c) {
#if __has_builtin(__builtin_amdgcn_sdot4)
  return __builtin_amdgcn_sdot4(a, b, c, false);
#else
  int s = c;
#pragma unroll
  for (int i = 0; i < 4; ++i)
    s += (int)(int8_t)(a >> (8 * i)) * (int)(int8_t)(b >> (8 * i));
  return s;
#endif
}

__device__ __forceinline__ int f32_to_i8c(float x) {
  int v = __float2int_rn(x);
  return v > 127 ? 127 : (v < -127 ? -127 : v);
}

// ---------------- Threefry2x32 (JAX-compatible), host+device ----------------
__host__ __device__ __forceinline__ void tf2x32(uint32_t k0, uint32_t k1,
                                                uint32_t x0, uint32_t x1,
                                                uint32_t &y0, uint32_t &y1) {
  const uint32_t ks2 = k0 ^ k1 ^ 0x1BD11BDAu;
  x0 += k0; x1 += k1;
#define TF_R(r) { x0 += x1; x1 = (x1 << (r)) | (x1 >> (32 - (r))); x1 ^= x0; }
  TF_R(13) TF_R(15) TF_R(26) TF_R(6)
  x0 += k1; x1 += ks2 + 1u;
  TF_R(17) TF_R(29) TF_R(16) TF_R(24)
  x0 += ks2; x1 += k0 + 2u;
  TF_R(13) TF_R(15) TF_R(26) TF_R(6)
  x0 += k0; x1 += k1 + 3u;
  TF_R(17) TF_R(29) TF_R(16) TF_R(24)
  x0 += k1; x1 += ks2 + 4u;
  TF_R(13) TF_R(15) TF_R(26) TF_R(6)
  x0 += ks2; x1 += k0 + 5u;
#undef TF_R
  y0 = x0; y1 = x1;
}

// ---------------- host-computed per-step constants ----------------
struct IdxParams {
  uint32_t k1x[NSTEP], k1y[NSTEP], k2x[NSTEP], k2y[NSTEP];
  uint32_t mult[NSTEP];
  uint32_t Msp[NSTEP], Ssp[NSTEP], Asp[NSTEP];   // magic for span = 8*T2
  uint32_t Mt2[NSTEP], St2[NSTEP], At2[NSTEP];   // magic for T2
};

// Hacker's Delight 10-9 unsigned magic
static void magicu(uint32_t d, uint32_t* M, uint32_t* s, uint32_t* a) {
  uint32_t p, nc, delta, q1, r1, q2, r2;
  *a = 0;
  nc = 0xFFFFFFFFu - (0u - d) % d;
  p = 31;
  q1 = 0x80000000u / nc; r1 = 0x80000000u - q1 * nc;
  q2 = 0x7FFFFFFFu / d;  r2 = 0x7FFFFFFFu - q2 * d;
  do {
    p = p + 1;
    if (r1 >= nc - r1) { q1 = 2*q1 + 1; r1 = 2*r1 - nc; }
    else               { q1 = 2*q1;     r1 = 2*r1; }
    if (r2 + 1 >= d - r2) {
      if (q2 >= 0x7FFFFFFFu) *a = 1;
      q2 = 2*q2 + 1; r2 = 2*r2 + 1 - d;
    } else {
      if (q2 >= 0x80000000u) *a = 1;
      q2 = 2*q2; r2 = 2*r2 + 1;
    }
    delta = d - 1 - r2;
  } while (p < 64 && (q1 < delta || (q1 == delta && r1 == 0)));
  *M = q2 + 1; *s = p - 32;
}

__device__ __forceinline__ uint32_t mdiv(uint32_t n, uint32_t M, uint32_t s, uint32_t a) {
  uint32_t q = __umulhi(n, M);
  if (a) { q = ((n - q) >> 1) + q; return q >> (s - 1); }
  return q >> s;
}

// ------------- prep: tgt-l2norm->i8, ctx->f16, W->f16, idx table -------------
// blocks [0,512): targets; [512,1024): ctx; [1024,1792): W; [1792,1792+9984): idx table.
__global__ __launch_bounds__(256) void prep_kernel(const IdxParams P,
                                                   const float* __restrict__ tgt,
                                                   const float* __restrict__ ctx,
                                                   const float* __restrict__ W,
                                                   int8_t* __restrict__ ti8,
                                                   _Float16* __restrict__ ctxh,
                                                   _Float16* __restrict__ Wh,
                                                   uint16_t* __restrict__ idxTab) {
  const int bx = blockIdx.x;
  const int tid = threadIdx.x;
  if (bx < 512) {                                        // tgt: normalize -> i8 (x127)
    const int lane = tid & 63;
    const int row = bx * 4 + (tid >> 6);
    float4 v = ((const float4*)(tgt + (size_t)row * DD))[lane];
    float ss = v.x*v.x + v.y*v.y + v.z*v.z + v.w*v.w;
#pragma unroll
    for (int off = 1; off < 64; off <<= 1) ss += __shfl_xor(ss, off, 64);
    const float sc = 127.0f / fmaxf(sqrtf(ss), 1e-12f);
    const uint32_t p = ((uint32_t)(f32_to_i8c(v.x * sc) & 255))
                     | ((uint32_t)(f32_to_i8c(v.y * sc) & 255) << 8)
                     | ((uint32_t)(f32_to_i8c(v.z * sc) & 255) << 16)
                     | ((uint32_t)(f32_to_i8c(v.w * sc) & 255) << 24);
    ((uint32_t*)(ti8 + (size_t)row * DD))[lane] = p;
  } else if (bx < 1792) {
    const int lane = tid & 63;
    union { _Float16 h[4]; uint2 u; } o;
    if (bx < 1024) {                                     // ctx: plain convert
      const int row = (bx - 512) * 4 + (tid >> 6);
      float4 v = ((const float4*)(ctx + (size_t)row * DD))[lane];
      o.h[0] = (_Float16)v.x; o.h[1] = (_Float16)v.y;
      o.h[2] = (_Float16)v.z; o.h[3] = (_Float16)v.w;
      ((uint2*)(ctxh + (size_t)row * DD))[lane] = o.u;
    } else {                                             // W: plain convert (3072 rows)
      const int row = (bx - 1024) * 4 + (tid >> 6);
      float4 v = ((const float4*)(W + (size_t)row * DD))[lane];
      o.h[0] = (_Float16)v.x; o.h[1] = (_Float16)v.y;
      o.h[2] = (_Float16)v.z; o.h[3] = (_Float16)v.w;
      ((uint2*)(Wh + (size_t)row * DD))[lane] = o.u;
    }
  } else {                                               // index table: 832 blocks per step
    const int ib = bx - 1792;                            // 0..9983
    const int si = ib / 832;                             // block-uniform -> scalar P loads
    const int step = si + 1;
    const uint32_t T2 = (uint32_t)(TT - step);
    const uint32_t nloc = (uint32_t)(ib - si * 832) * 256u + (uint32_t)tid;  // 0..212991
    const uint32_t m = nloc / 104u;                      // b*256 + t
    const uint32_t slot = nloc - m * 104u;
    const uint32_t t = m & 255u;
    const uint32_t b = m >> 8;
    uint32_t v = 0u;
    if (t < T2 && slot <= (uint32_t)NNEG) {
      if (slot == 0u) {
        v = b * TT + t + (uint32_t)step;                 // positive row
      } else {
        const uint32_t j = (b * T2 + t) * NNEG + (slot - 1u);
        uint32_t h0, h1, l0, l1;
        tf2x32(P.k1x[si], P.k1y[si], 0u, j, h0, h1);
        tf2x32(P.k2x[si], P.k2y[si], 0u, j, l0, l1);
        const uint32_t span = 8u * T2;
        const uint32_t Msp = P.Msp[si], Ssp = P.Ssp[si], Asp = P.Asp[si];
        const uint32_t hm = h0 - mdiv(h0, Msp, Ssp, Asp) * span;
        const uint32_t lm = l0 - mdiv(l0, Msp, Ssp, Asp) * span;
        const uint32_t off = hm * P.mult[si] + lm;
        const uint32_t om = off - mdiv(off, Msp, Ssp, Asp) * span;
        const uint32_t bbq = mdiv(om, P.Mt2[si], P.St2[si], P.At2[si]);
        const uint32_t tt = om - bbq * T2;
        v = bbq * TT + tt + (uint32_t)step;
      }
    }
    idxTab[(size_t)si * (2048u * 104u) + nloc] = (uint16_t)v;
  }
}

// ------------- query GEMM (MFMA f16) + bias + l2norm -> i8 (x127) -------------
// grid (64 m-tiles of 32 rows, 12 steps), block 256 = 4 waves.
__global__ __launch_bounds__(256) void qgemm_mfma_kernel(const _Float16* __restrict__ ctxh,
                                                         const _Float16* __restrict__ Wh,
                                                         const float* __restrict__ bias,
                                                         int8_t* __restrict__ qi8) {
  const int mt  = blockIdx.x;           // 0..63
  const int s   = blockIdx.y;           // 0..11
  const int tid = threadIdx.x;
  const int w   = tid >> 6;
  const int lane = tid & 63;
  const int sl = lane & 15;
  const int q  = lane >> 4;
  const int m0 = mt * 32;

  const _Float16* Arow0 = ctxh + ((size_t)(m0 + sl)) * DD + q * 8;
  const _Float16* Arow1 = Arow0 + (size_t)16 * DD;
  const _Float16* Bbase = Wh + (size_t)s * DD * DD + ((size_t)(w * 64 + sl)) * DD + q * 8;

  f32x4 acc[2][4];
#pragma unroll
  for (int mi = 0; mi < 2; ++mi)
#pragma unroll
    for (int nt = 0; nt < 4; ++nt) acc[mi][nt] = f32x4{0, 0, 0, 0};

#pragma unroll
  for (int k0 = 0; k0 < 8; ++k0) {
    const f16x8 a0 = *(const f16x8*)(Arow0 + k0 * 32);
    const f16x8 a1 = *(const f16x8*)(Arow1 + k0 * 32);
#pragma unroll
    for (int nt = 0; nt < 4; ++nt) {
      const f16x8 b = *(const f16x8*)(Bbase + (size_t)nt * 16 * DD + k0 * 32);
      acc[0][nt] = __builtin_amdgcn_mfma_f32_16x16x32_f16(a0, b, acc[0][nt], 0, 0, 0);
      acc[1][nt] = __builtin_amdgcn_mfma_f32_16x16x32_f16(a1, b, acc[1][nt], 0, 0, 0);
    }
  }
  const float* bp = bias + (size_t)s * DD + w * 64 + sl;
  __shared__ float part[4][32];
#pragma unroll
  for (int mi = 0; mi < 2; ++mi) {
#pragma unroll
    for (int nt = 0; nt < 4; ++nt) {
      const float bv = bp[nt * 16];
#pragma unroll
      for (int r = 0; r < 4; ++r) acc[mi][nt][r] += bv;
    }
    float ss[4];
#pragma unroll
    for (int r = 0; r < 4; ++r) {
      float v = 0.f;
#pragma unroll
      for (int nt = 0; nt < 4; ++nt) v += acc[mi][nt][r] * acc[mi][nt][r];
      ss[r] = v;
    }
#pragma unroll
    for (int off = 1; off < 16; off <<= 1) {
#pragma unroll
      for (int r = 0; r < 4; ++r) ss[r] += __shfl_xor(ss[r], off, 64);
    }
    if (sl == 0) {
#pragma unroll
      for (int r = 0; r < 4; ++r) part[w][mi * 16 + q * 4 + r] = ss[r];
    }
  }
  __syncthreads();
#pragma unroll
  for (int mi = 0; mi < 2; ++mi) {
#pragma unroll
    for (int r = 0; r < 4; ++r) {
      const int row = q * 4 + r;
      const float tot = part[0][mi * 16 + row] + part[1][mi * 16 + row]
                      + part[2][mi * 16 + row] + part[3][mi * 16 + row];
      const float sc = 127.0f / fmaxf(sqrtf(tot), 1e-12f);
      int8_t* outp = qi8 + (((size_t)s * (BB * TT)) + m0 + mi * 16 + row) * DD + w * 64 + sl;
#pragma unroll
      for (int nt = 0; nt < 4; ++nt)
        outp[nt * 16] = (int8_t)f32_to_i8c(acc[mi][nt][r] * sc);
    }
  }
}

// ------------- scoring: idxTab load + i8 gather + sdot4 + log-softmax -------------
// R0 structure (proven 50.8us) minus inline threefry, fdot2->sdot4.
__global__ __launch_bounds__(128) void score_kernel(const int8_t* __restrict__ qi8,
                                                    const int8_t* __restrict__ ti8,
                                                    const uint16_t* __restrict__ idxTab,
                                                    float* __restrict__ partial) {
  const int t    = blockIdx.x;            // 0..254
  const int b    = blockIdx.y;
  const int si   = blockIdx.z;
  const int step = si + 1;
  const int T2   = TT - step;
  const int lin  = (si * BB + b) * 255 + t;
  const int tid  = threadIdx.x;
  if (t >= T2) { if (tid == 0) partial[lin] = 0.f; return; }

  __shared__ int   rowIdx[NNEG + 1];
  __shared__ float logit[NNEG + 1];

  if (tid <= NNEG)
    rowIdx[tid] = (int)idxTab[((size_t)si * 2048 + b * 256 + t) * SLOTP + tid];

  const int g  = tid >> 2;                // dot-group 0..31
  const int gl = tid & 3;                 // lane-in-group
  const int8_t* qrow = qi8 + ((size_t)si * 2048 + b * 256 + t) * DD;
  uint4 qv[4];
#pragma unroll
  for (int c = 0; c < 4; ++c)
    qv[c] = *(const uint4*)(qrow + c * 64 + gl * 16);
  __syncthreads();

#pragma unroll
  for (int r = 0; r < 4; ++r) {
    const int k = r * 32 + g;
    if (k <= NNEG) {
      const int8_t* prow = ti8 + (size_t)rowIdx[k] * DD;
      int acc = 0;
#pragma unroll
      for (int c = 0; c < 4; ++c) {
        const uint4 pv = *(const uint4*)(prow + c * 64 + gl * 16);
        acc = sdot4((int)qv[c].x, (int)pv.x, acc);
        acc = sdot4((int)qv[c].y, (int)pv.y, acc);
        acc = sdot4((int)qv[c].z, (int)pv.z, acc);
        acc = sdot4((int)qv[c].w, (int)pv.w, acc);
      }
      acc += __shfl_xor(acc, 1, 64);
      acc += __shfl_xor(acc, 2, 64);
      if (gl == 0) logit[k] = (float)acc * (10.0f / 16129.0f);  // /(127^2) * 1/TEMP
    }
  }
  __syncthreads();

  if (tid < 64) {
    const int lane = tid;
    const float a = logit[lane];
    const float c = (lane + 64 <= NNEG) ? logit[lane + 64] : -1e30f;
    float m = fmaxf(a, c);
#pragma unroll
    for (int off = 1; off < 64; off <<= 1) m = fmaxf(m, __shfl_xor(m, off, 64));
    float e = __expf(a - m) + ((lane + 64 <= NNEG) ? __expf(c - m) : 0.f);
#pragma unroll
    for (int off = 1; off < 64; off <<= 1) e += __shfl_xor(e, off, 64);
    if (lane == 0) {
      const float lse = m + logf(e);
      partial[lin] = (lse - logit[0]) / (12.0f * (float)(BB * T2));
    }
  }
}

// ---------------- final reduction ----------------
__global__ __launch_bounds__(1024) void final_sum_kernel(const float* __restrict__ partial,
                                                         float* __restrict__ out) {
  __shared__ float wsum[16];
  const int tid = threadIdx.x;
  float s = 0.f;
  const float4* p4 = (const float4*)partial;
  for (int i = tid; i < NPART / 4; i += 1024) {
    const float4 v = p4[i];
    s += v.x + v.y + v.z + v.w;
  }
#pragma unroll
  for (int off = 1; off < 64; off <<= 1) s += __shfl_xor(s, off, 64);
  if ((tid & 63) == 0) wsum[tid >> 6] = s;
  __syncthreads();
  if (tid == 0) {
    float tot = 0.f;
#pragma unroll
    for (int i = 0; i < 16; ++i) tot += wsum[i];
    out[0] = tot;
  }
}

extern "C" void kernel_launch(void* const* d_in, const int* in_sizes, int n_in,
                              void* d_out, int out_size, void* d_ws, size_t ws_size,
                              hipStream_t stream) {
  const float* ctx  = (const float*)d_in[0];
  const float* tgt  = (const float*)d_in[1];
  const float* W    = (const float*)d_in[2];
  const float* bias = (const float*)d_in[3];
  float* out = (float*)d_out;

  int8_t* ti8    = (int8_t*)d_ws;                                // 512 KB
  _Float16* ctxh = (_Float16*)(ti8 + (size_t)BB * TT * DD);      // 1 MB
  _Float16* Wh   = ctxh + (size_t)BB * TT * DD;                  // 1.5 MB
  int8_t* qi8    = (int8_t*)(Wh + (size_t)NSTEP * DD * DD);      // 6.29 MB
  uint16_t* idxTab = (uint16_t*)(qi8 + (size_t)NSTEP * BB * TT * DD); // 5.11 MB
  float* partial = (float*)(idxTab + (size_t)NSTEP * 2048 * SLOTP);   // 98 KB

  // host-side per-step constants (deterministic; same every call)
  IdxParams P;
  for (int s = 0; s < NSTEP; ++s) {
    uint32_t a, b;
    tf2x32(0u, 1234u, 0u, (uint32_t)(s + 1), a, b);              // fold_in(key(1234), step)
    uint32_t h1a, h1b, h2a, h2b;
    tf2x32(a, b, 0u, 2u, h1a, h1b);                              // split -> k1
    tf2x32(a, b, 1u, 3u, h2a, h2b);                              // split -> k2
    P.k1x[s] = h1a; P.k1y[s] = h1b; P.k2x[s] = h2a; P.k2y[s] = h2b;
    const uint32_t T2 = (uint32_t)(TT - (s + 1));
    const uint32_t span = 8u * T2;
    uint32_t m = 65536u % span;
    P.mult[s] = (uint32_t)(((uint64_t)m * m) % span);
    magicu(span, &P.Msp[s], &P.Ssp[s], &P.Asp[s]);
    magicu(T2,   &P.Mt2[s], &P.St2[s], &P.At2[s]);
  }

  hipLaunchKernelGGL(prep_kernel, dim3(1792 + 12 * 832), dim3(256), 0, stream,
                     P, tgt, ctx, W, ti8, ctxh, Wh, idxTab);
  hipLaunchKernelGGL(qgemm_mfma_kernel, dim3(64, NSTEP), dim3(256), 0, stream,
                     ctxh, Wh, bias, qi8);
  hipLaunchKernelGGL(score_kernel, dim3(255, BB, NSTEP), dim3(128), 0, stream,
                     qi8, ti8, idxTab, partial);
  hipLaunchKernelGGL(final_sum_kernel, dim3(1), dim3(1024), 0, stream, partial, out);
}